// Round 2
// baseline (841.975 us; speedup 1.0000x reference)
//
#include <hip/hip_runtime.h>

typedef unsigned short u16;
typedef short s16x8 __attribute__((ext_vector_type(8)));
typedef float f32x4 __attribute__((ext_vector_type(4)));

#define DEVI static __device__ __forceinline__
#define MFMA16(A, B, C) __builtin_amdgcn_mfma_f32_16x16x32_bf16(A, B, C, 0, 0, 0)
#define Z4 ((f32x4){0.f, 0.f, 0.f, 0.f})

DEVI float bf2f(u16 u) {
  unsigned int x = ((unsigned int)u) << 16;
  float f; __builtin_memcpy(&f, &x, 4); return f;
}
DEVI u16 f2bf(float f) {
  unsigned int u; __builtin_memcpy(&u, &f, 4);
  u += 0x7fffu + ((u >> 16) & 1u);
  return (u16)(u >> 16);
}
DEVI float sigmoidf_(float x) { return 1.0f / (1.0f + __expf(-x)); }
DEVI float tanhf_(float x) { return 1.0f - 2.0f / (__expf(2.0f * x) + 1.0f); }

// ---------------- weight f32 -> bf16 ----------------
__global__ void k_f2bf(const float* __restrict__ X, u16* __restrict__ Y, int n) {
  int i = blockIdx.x * blockDim.x + threadIdx.x;
  if (i < n) Y[i] = f2bf(X[i]);
}

// =================================================================
// Phase 1: fused  QKV-proj -> QK^T -> softmax -> PV -> out-proj
// One block per n (2048 blocks), 512 threads (8 waves).
// Math note: channel/spatial attention collapse to identity
// (softmax over size-1 axes == 1), so fused = 2*input exactly.
// sides: 0 = T (q,v from text, k from graph), 1 = G.
// LDS (u16 offsets):
//   QB2 [2][32][264] @ 0      (Q of side s; reused as O staging after QK)
//   KB2 [2][32][264] @ 16896  (K of side s)
//   VT2 [2][256][40] @ 33792  (V transposed: (e, m))
//   SF2 f32[2][32][34] @ 54272 (scores)
//   PB2 [2][32][40] @ 58624   (softmax P, bf16)
// total 61184 u16 = 119.5 KB
// =================================================================
#define QB2 0
#define KB2 16896
#define VT2 33792
#define SF2 54272
#define PB2 58624

__global__ __launch_bounds__(512, 1) void k_attn(
    const float* __restrict__ inT, const float* __restrict__ inG,
    const u16* __restrict__ Wproj, const float* __restrict__ bproj,
    const u16* __restrict__ Wout, const float* __restrict__ bout,
    u16* __restrict__ attT, u16* __restrict__ attG) {
  __shared__ u16 sh[61184];
  int n = blockIdx.x;
  int tid = threadIdx.x;
  int w = tid >> 6, lane = tid & 63;
  int lr = lane & 15, kg = lane >> 4;
  int sw = w >> 2, wq = w & 3;

  // ---- (b) QKV projection: A = 2*input rows (global f32 -> bf16 regs) ----
  {
    const float* inS = sw ? inG : inT;
    s16x8 aS[2][8];
#pragma unroll
    for (int mt = 0; mt < 2; ++mt)
#pragma unroll
      for (int k = 0; k < 8; ++k) {
        const float* p = inS + ((long)(mt * 16 + lr) * 2048 + n) * 256 + k * 32 + kg * 8;
        f32x4 v0 = *(const f32x4*)p;
        f32x4 v1 = *(const f32x4*)(p + 4);
        s16x8 t;
        t[0] = (short)f2bf(2.f * v0[0]); t[1] = (short)f2bf(2.f * v0[1]);
        t[2] = (short)f2bf(2.f * v0[2]); t[3] = (short)f2bf(2.f * v0[3]);
        t[4] = (short)f2bf(2.f * v1[0]); t[5] = (short)f2bf(2.f * v1[1]);
        t[6] = (short)f2bf(2.f * v1[2]); t[7] = (short)f2bf(2.f * v1[3]);
        aS[mt][k] = t;
      }
    // 12 N-tiles per wave over cols [wq*192, wq*192+192) of 768 (Q|K|V)
    for (int i = 0; i < 12; ++i) {
      int col0 = (wq * 12 + i) * 16;
      const u16* wp = Wproj + (long)(col0 + lr) * 256 + kg * 8;
      s16x8 b[8];
#pragma unroll
      for (int k = 0; k < 8; ++k) b[k] = *(const s16x8*)(wp + k * 32);
      f32x4 a0 = Z4, a1 = Z4;
#pragma unroll
      for (int k = 0; k < 8; ++k) {
        a0 = MFMA16(aS[0][k], b[k], a0);
        a1 = MFMA16(aS[1][k], b[k], a1);
      }
      int col = col0 + lr;
      float bias = bproj[col];
      if (col < 512) {
        u16* base = sh + (col < 256 ? (QB2 + sw * 8448 + col)
                                    : (KB2 + sw * 8448 + col - 256));
#pragma unroll
        for (int j = 0; j < 4; ++j) {
          base[(kg * 4 + j) * 264] = f2bf(a0[j] + bias);
          base[(16 + kg * 4 + j) * 264] = f2bf(a1[j] + bias);
        }
      } else {
        u16* base = sh + VT2 + sw * 10240 + (col - 512) * 40;
#pragma unroll
        for (int j = 0; j < 4; ++j) {
          base[kg * 4 + j] = f2bf(a0[j] + bias);
          base[16 + kg * 4 + j] = f2bf(a1[j] + bias);
        }
      }
    }
  }
  __syncthreads();

  // ---- (c) scores_s = Q_s . K_{1-s}^T / 16 ----
  {
    int s = sw, mt = (w >> 1) & 1, mh = w & 1;
    f32x4 acc = Z4;
#pragma unroll
    for (int k = 0; k < 8; ++k) {
      s16x8 qa = *(const s16x8*)(sh + QB2 + s * 8448 + (mt * 16 + lr) * 264 + k * 32 + kg * 8);
      s16x8 kb = *(const s16x8*)(sh + KB2 + (1 - s) * 8448 + (mh * 16 + lr) * 264 + k * 32 + kg * 8);
      acc = MFMA16(qa, kb, acc);
    }
    float* Sfp = (float*)(sh + SF2) + s * 1088 + mh * 16 + lr;
#pragma unroll
    for (int j = 0; j < 4; ++j)
      Sfp[(mt * 16 + kg * 4 + j) * 34] = acc[j] * 0.0625f;
  }
  __syncthreads();

  // ---- (d) softmax over m (rows of 32) ----
  if (tid < 64) {
    int s = tid >> 5, l = tid & 31;
    float* Sp = (float*)(sh + SF2) + s * 1088 + l * 34;
    float mx = -1e30f;
#pragma unroll
    for (int m = 0; m < 32; ++m) mx = fmaxf(mx, Sp[m]);
    float e[32]; float sum = 0.f;
#pragma unroll
    for (int m = 0; m < 32; ++m) { e[m] = __expf(Sp[m] - mx); sum += e[m]; }
    float inv = 1.f / sum;
    u16* Pp = sh + PB2 + s * 1280 + l * 40;
#pragma unroll
    for (int m = 0; m < 32; ++m) Pp[m] = f2bf(e[m] * inv);
  }
  __syncthreads();

  // ---- (e) O_s = P_s . V_s  (writes O into QB2 region; Q is dead) ----
  {
    s16x8 pa0 = *(const s16x8*)(sh + PB2 + sw * 1280 + lr * 40 + kg * 8);
    s16x8 pa1 = *(const s16x8*)(sh + PB2 + sw * 1280 + (16 + lr) * 40 + kg * 8);
#pragma unroll
    for (int i = 0; i < 4; ++i) {
      int e0 = (wq * 4 + i) * 16;
      s16x8 vb = *(const s16x8*)(sh + VT2 + sw * 10240 + (e0 + lr) * 40 + kg * 8);
      f32x4 a0 = MFMA16(pa0, vb, Z4);
      f32x4 a1 = MFMA16(pa1, vb, Z4);
      u16* base = sh + QB2 + sw * 8448 + e0 + lr;
#pragma unroll
      for (int j = 0; j < 4; ++j) {
        base[(kg * 4 + j) * 264] = f2bf(a0[j]);
        base[(16 + kg * 4 + j) * 264] = f2bf(a1[j]);
      }
    }
  }
  __syncthreads();

  // ---- (f) att_s = O_s @ Wout^T + bout -> global bf16 ----
  {
    s16x8 ao[2][8];
#pragma unroll
    for (int mt = 0; mt < 2; ++mt)
#pragma unroll
      for (int k = 0; k < 8; ++k)
        ao[mt][k] = *(const s16x8*)(sh + QB2 + sw * 8448 + (mt * 16 + lr) * 264 + k * 32 + kg * 8);
    u16* dst = sw ? attG : attT;
#pragma unroll
    for (int i = 0; i < 4; ++i) {
      int colb = (wq * 4 + i) * 16;
      const u16* wp = Wout + (long)(colb + lr) * 256 + kg * 8;
      s16x8 b[8];
#pragma unroll
      for (int k = 0; k < 8; ++k) b[k] = *(const s16x8*)(wp + k * 32);
      f32x4 a0 = Z4, a1 = Z4;
#pragma unroll
      for (int k = 0; k < 8; ++k) {
        a0 = MFMA16(ao[0][k], b[k], a0);
        a1 = MFMA16(ao[1][k], b[k], a1);
      }
      long cb = colb + lr;
      float bias = bout[cb];
#pragma unroll
      for (int j = 0; j < 4; ++j) {
        dst[((long)(kg * 4 + j) * 2048 + n) * 256 + cb] = f2bf(a0[j] + bias);
        dst[((long)(16 + kg * 4 + j) * 2048 + n) * 256 + cb] = f2bf(a1[j] + bias);
      }
    }
  }
}

// =================================================================
// Phase 2: fused  H=attT*attG -> inter=H@Wlin^T -> gi/gh1/gh2 -> GRU
// One block per 64 rows (1024 blocks), 512 threads (8 waves).
// wave: rows (w&3)*16, col-half (w>>2)*128.
// LDS: AT [64][264] @0, AG @16896, HI @33792 (H, then inter in-place)
// =================================================================
__global__ __launch_bounds__(512, 1) void k_gru(
    const u16* __restrict__ attT, const u16* __restrict__ attG,
    const u16* __restrict__ Wlin, const float* __restrict__ blin,
    const u16* __restrict__ Wih, const float* __restrict__ bih,
    const u16* __restrict__ Whh, const float* __restrict__ bhh,
    u16* __restrict__ g1, u16* __restrict__ g2) {
  __shared__ u16 sh[50688];
  const int AT = 0, AG = 16896, HI = 33792;
  long m0 = (long)blockIdx.x * 64;
  int tid = threadIdx.x, w = tid >> 6, lane = tid & 63;
  int lr = lane & 15, kg = lane >> 4;

  // load att rows + elementwise product
  {
    int r = tid >> 3, q = tid & 7;
    const u16* st = attT + (m0 + r) * 256;
    const u16* sg = attG + (m0 + r) * 256;
#pragma unroll
    for (int i = 0; i < 4; ++i) {
      int e = i * 64 + q * 8;
      s16x8 vt = *(const s16x8*)(st + e);
      s16x8 vg = *(const s16x8*)(sg + e);
      *(s16x8*)(sh + AT + r * 264 + e) = vt;
      *(s16x8*)(sh + AG + r * 264 + e) = vg;
      s16x8 vh;
#pragma unroll
      for (int j = 0; j < 8; ++j)
        vh[j] = (short)f2bf(bf2f((u16)vt[j]) * bf2f((u16)vg[j]));
      *(s16x8*)(sh + HI + r * 264 + e) = vh;
    }
  }
  __syncthreads();

  int rw = (w & 3) * 16, ch = (w >> 2);

  // inter = H @ Wlin^T + blin  (in-place into HI; A preloaded first)
  {
    s16x8 aH[8];
#pragma unroll
    for (int k = 0; k < 8; ++k)
      aH[k] = *(const s16x8*)(sh + HI + (rw + lr) * 264 + k * 32 + kg * 8);
    __syncthreads();  // everyone's H reads done before inter overwrites
    for (int i = 0; i < 8; ++i) {
      int colb = (ch * 8 + i) * 16;
      const u16* wp = Wlin + (long)(colb + lr) * 256 + kg * 8;
      s16x8 b[8];
#pragma unroll
      for (int k = 0; k < 8; ++k) b[k] = *(const s16x8*)(wp + k * 32);
      f32x4 acc = Z4;
#pragma unroll
      for (int k = 0; k < 8; ++k) acc = MFMA16(aH[k], b[k], acc);
      float bias = blin[colb + lr];
      u16* base = sh + HI + colb + lr;
#pragma unroll
      for (int j = 0; j < 4; ++j)
        base[(rw + kg * 4 + j) * 264] = f2bf(acc[j] + bias);
    }
  }
  __syncthreads();

  // gate GEMMs + GRU elementwise
  s16x8 aI[8], aT8[8], aG8[8];
#pragma unroll
  for (int k = 0; k < 8; ++k) {
    aI[k] = *(const s16x8*)(sh + HI + (rw + lr) * 264 + k * 32 + kg * 8);
    aT8[k] = *(const s16x8*)(sh + AT + (rw + lr) * 264 + k * 32 + kg * 8);
    aG8[k] = *(const s16x8*)(sh + AG + (rw + lr) * 264 + k * 32 + kg * 8);
  }
  for (int ic = 0; ic < 8; ++ic) {
    int col = (ch * 8 + ic) * 16 + lr;
    f32x4 acc[3][3];
#pragma unroll
    for (int g = 0; g < 3; ++g)
#pragma unroll
      for (int s2 = 0; s2 < 3; ++s2) acc[g][s2] = Z4;
#pragma unroll
    for (int g = 0; g < 3; ++g) {
      const u16* bi = Wih + (long)(g * 256 + col) * 256 + kg * 8;
      const u16* bh = Whh + (long)(g * 256 + col) * 256 + kg * 8;
#pragma unroll
      for (int k = 0; k < 8; ++k) {
        s16x8 bI = *(const s16x8*)(bi + k * 32);
        s16x8 bH = *(const s16x8*)(bh + k * 32);
        acc[g][0] = MFMA16(aI[k], bI, acc[g][0]);
        acc[g][1] = MFMA16(aT8[k], bH, acc[g][1]);
        acc[g][2] = MFMA16(aG8[k], bH, acc[g][2]);
      }
    }
    float bir = bih[col], biz = bih[col + 256], bin = bih[col + 512];
    float bhr = bhh[col], bhz = bhh[col + 256], bhn = bhh[col + 512];
#pragma unroll
    for (int j = 0; j < 4; ++j) {
      int row = rw + kg * 4 + j;
      float hT = bf2f(sh[AT + row * 264 + col]);
      float hG = bf2f(sh[AG + row * 264 + col]);
      float ir = acc[0][0][j] + bir;
      float iz = acc[1][0][j] + biz;
      float inn = acc[2][0][j] + bin;
      float r1 = sigmoidf_(ir + acc[0][1][j] + bhr);
      float z1 = sigmoidf_(iz + acc[1][1][j] + bhz);
      float n1 = tanhf_(inn + r1 * (acc[2][1][j] + bhn));
      float o1 = (1.f - z1) * n1 + z1 * hT;
      float r2 = sigmoidf_(ir + acc[0][2][j] + bhr);
      float z2 = sigmoidf_(iz + acc[1][2][j] + bhz);
      float n2 = tanhf_(inn + r2 * (acc[2][2][j] + bhn));
      float o2 = (1.f - z2) * n2 + z2 * hG;
      long off = (m0 + row) * 256 + col;
      g1[off] = f2bf(o1);
      g2[off] = f2bf(o2);
    }
  }
}

// =================================================================
// Phase 3: out = relu(conv7x7(g1)+b) + relu(conv7x7(g2)+b), f32 out
// tile 32(s) x 64(e) per block, zero-padded boundaries
// =================================================================
__global__ __launch_bounds__(256) void k_conv(
    const u16* __restrict__ g1, const u16* __restrict__ g2,
    const float* __restrict__ wss, const float* __restrict__ bss,
    float* __restrict__ out) {
  __shared__ float s1[38][73];
  __shared__ float s2[38][73];
  int et = blockIdx.x, st = blockIdx.y, b = blockIdx.z;
  int s0 = st * 32, e0 = et * 64;
  int tid = threadIdx.x;
  for (int idx = tid; idx < 38 * 70; idx += 256) {
    int r = idx / 70, c = idx % 70;
    int s = s0 + r - 3, e = e0 + c - 3;
    float v1 = 0.f, v2 = 0.f;
    if (s >= 0 && s < 2048 && e >= 0 && e < 256) {
      long off = ((long)b * 2048 + s) * 256 + e;
      v1 = bf2f(g1[off]); v2 = bf2f(g2[off]);
    }
    s1[r][c] = v1; s2[r][c] = v2;
  }
  __syncthreads();
  float bias = bss[0];
  int oy = tid >> 3, ox = (tid & 7) * 8;
  float a1[8] = {0.f, 0.f, 0.f, 0.f, 0.f, 0.f, 0.f, 0.f};
  float a2[8] = {0.f, 0.f, 0.f, 0.f, 0.f, 0.f, 0.f, 0.f};
#pragma unroll
  for (int ky = 0; ky < 7; ++ky) {
    float wr[7];
#pragma unroll
    for (int kx = 0; kx < 7; ++kx) wr[kx] = wss[ky * 7 + kx];
    float r1[14], r2[14];
#pragma unroll
    for (int j = 0; j < 14; ++j) { r1[j] = s1[oy + ky][ox + j]; r2[j] = s2[oy + ky][ox + j]; }
#pragma unroll
    for (int x = 0; x < 8; ++x)
#pragma unroll
      for (int kx = 0; kx < 7; ++kx) {
        a1[x] += r1[x + kx] * wr[kx];
        a2[x] += r2[x + kx] * wr[kx];
      }
  }
  long obase = ((long)b * 2048 + s0 + oy) * 256 + e0 + ox;
  f32x4 o0, o1;
#pragma unroll
  for (int x = 0; x < 4; ++x) {
    o0[x] = fmaxf(a1[x] + bias, 0.f) + fmaxf(a2[x] + bias, 0.f);
    o1[x] = fmaxf(a1[x + 4] + bias, 0.f) + fmaxf(a2[x + 4] + bias, 0.f);
  }
  *(f32x4*)(out + obase) = o0;
  *(f32x4*)(out + obase + 4) = o1;
}

extern "C" void kernel_launch(void* const* d_in, const int* in_sizes, int n_in,
                              void* d_out, int out_size, void* d_ws, size_t ws_size,
                              hipStream_t stream) {
  const float* text = (const float*)d_in[0];
  const float* graph = (const float*)d_in[1];
  // d_in[2..7] (avg_*/max_*/sp_*) are mathematically dead:
  // softmax over size-1 axes == 1 -> fused = 2*input exactly.
  const float* in_proj_w = (const float*)d_in[8];
  const float* in_proj_b = (const float*)d_in[9];
  const float* out_w = (const float*)d_in[10];
  const float* out_b = (const float*)d_in[11];
  const float* lin_w = (const float*)d_in[12];
  const float* lin_b = (const float*)d_in[13];
  const float* w_ih = (const float*)d_in[14];
  const float* w_hh = (const float*)d_in[15];
  const float* b_ih = (const float*)d_in[16];
  const float* b_hh = (const float*)d_in[17];
  const float* ssf_w = (const float*)d_in[18];
  const float* ssf_b = (const float*)d_in[19];

  // ws: g1 (32MB) | g2 (32MB) | bf16 weights (~1.4MB)   => ~65.5MB total
  u16* g1 = (u16*)d_ws;
  u16* g2 = g1 + 16777216;
  u16* Wproj = g2 + 16777216;
  u16* Wout = Wproj + 196608;
  u16* Wlin = Wout + 65536;
  u16* Wih = Wlin + 65536;
  u16* Whh = Wih + 196608;

  // d_out (64MB f32) doubles as bf16 scratch for attT/attG;
  // k_conv fully rewrites it as f32 at the end.
  u16* attT = (u16*)d_out;
  u16* attG = attT + 16777216;

  k_f2bf<<<768, 256, 0, stream>>>(in_proj_w, Wproj, 196608);
  k_f2bf<<<256, 256, 0, stream>>>(out_w, Wout, 65536);
  k_f2bf<<<256, 256, 0, stream>>>(lin_w, Wlin, 65536);
  k_f2bf<<<768, 256, 0, stream>>>(w_ih, Wih, 196608);
  k_f2bf<<<768, 256, 0, stream>>>(w_hh, Whh, 196608);

  k_attn<<<2048, 512, 0, stream>>>(text, graph, Wproj, in_proj_b, Wout, out_b, attT, attG);
  k_gru<<<1024, 512, 0, stream>>>(attT, attG, Wlin, lin_b, Wih, b_ih, Whh, b_hh, g1, g2);
  k_conv<<<dim3(4, 64, 32), 256, 0, stream>>>(g1, g2, ssf_w, ssf_b, (float*)d_out);
}